// Round 7
// baseline (1466.286 us; speedup 1.0000x reference)
//
#include <hip/hip_runtime.h>
#include <stdint.h>

#define EPS_LN 1e-5f

typedef short bf16x8 __attribute__((ext_vector_type(8)));
typedef float f32x4  __attribute__((ext_vector_type(4)));

__device__ __forceinline__ unsigned short f2bf(float f) {
    unsigned u = __float_as_uint(f);
    unsigned r = (u + 0x7fffu + ((u >> 16) & 1u)) >> 16;
    return (unsigned short)r;
}
__device__ __forceinline__ float bf_lo(unsigned u) { return __uint_as_float(u << 16); }
__device__ __forceinline__ float bf_hi(unsigned u) { return __uint_as_float(u & 0xffff0000u); }

__device__ __forceinline__ void async16(void* lds, const void* g) {
    __builtin_amdgcn_global_load_lds(
        (const __attribute__((address_space(1))) unsigned int*)g,
        (__attribute__((address_space(3))) unsigned int*)lds, 16, 0, 0);
}

// ---------------- degree / CSR construction ----------------

__global__ void count_deg_kernel(const int* __restrict__ dst, int E, unsigned* __restrict__ deg) {
    int e = blockIdx.x * blockDim.x + threadIdx.x;
    if (e < E) atomicAdd(&deg[dst[e]], 1u);
}

__global__ void block_sums_kernel(const unsigned* __restrict__ deg, unsigned* __restrict__ part, int N) {
    __shared__ unsigned s[256];
    int t = threadIdx.x;
    int i0 = blockIdx.x * 512 + t * 2;
    unsigned a = (i0 < N) ? deg[i0] : 0u;
    unsigned b = (i0 + 1 < N) ? deg[i0 + 1] : 0u;
    s[t] = a + b;
    __syncthreads();
    for (int off = 128; off > 0; off >>= 1) {
        if (t < off) s[t] += s[t + off];
        __syncthreads();
    }
    if (t == 0) part[blockIdx.x] = s[0];
}

__global__ void scan_part_kernel(unsigned* __restrict__ part, unsigned* __restrict__ row_ptr,
                                 int NB, int N) {
    __shared__ unsigned s[256];
    int t = threadIdx.x;
    unsigned v = (t < NB) ? part[t] : 0u;
    s[t] = v;
    __syncthreads();
    for (int off = 1; off < 256; off <<= 1) {
        unsigned u = (t >= off) ? s[t - off] : 0u;
        __syncthreads();
        s[t] += u;
        __syncthreads();
    }
    if (t < NB) part[t] = s[t] - v;
    if (t == 255) row_ptr[N] = s[255];
}

// local scan + row_ptr/cursor + dinv (merged)
__global__ void scan_blocks_kernel(const unsigned* __restrict__ deg, const unsigned* __restrict__ part,
                                   unsigned* __restrict__ row_ptr, unsigned* __restrict__ cursor,
                                   float* __restrict__ dinv, int N) {
    __shared__ unsigned s[256];
    int t = threadIdx.x;
    int i0 = blockIdx.x * 512 + t * 2;
    unsigned a = (i0 < N) ? deg[i0] : 0u;
    unsigned b = (i0 + 1 < N) ? deg[i0 + 1] : 0u;
    unsigned pair = a + b;
    s[t] = pair;
    __syncthreads();
    for (int off = 1; off < 256; off <<= 1) {
        unsigned u = (t >= off) ? s[t - off] : 0u;
        __syncthreads();
        s[t] += u;
        __syncthreads();
    }
    unsigned excl = s[t] - pair + part[blockIdx.x];
    if (i0 < N) {
        row_ptr[i0] = excl; cursor[i0] = excl;
        dinv[i0] = rsqrtf((float)(a + 1u));
    }
    if (i0 + 1 < N) {
        row_ptr[i0 + 1] = excl + a; cursor[i0 + 1] = excl + a;
        dinv[i0 + 1] = rsqrtf((float)(b + 1u));
    }
}

__global__ void fill_csr_kernel(const int* __restrict__ src, const int* __restrict__ dst,
                                const float* __restrict__ dinv, int E,
                                unsigned* __restrict__ cursor, uint2* __restrict__ csr) {
    int e = blockIdx.x * blockDim.x + threadIdx.x;
    if (e < E) {
        int d = dst[e];
        int s = src[e];
        unsigned pos = atomicAdd(&cursor[d], 1u);
        float w = dinv[d] * dinv[s];
        csr[pos] = make_uint2((unsigned)s, __float_as_uint(w));
    }
}

// ---------------- fused prep: x->bf16 + 3 weight transposes ----------------
__global__ void prep_all_kernel(const float* __restrict__ x, unsigned* __restrict__ xbf,
                                const float* __restrict__ W_in, unsigned short* __restrict__ Wt_in,
                                const float* __restrict__ W_hid, unsigned short* __restrict__ Wt_h0,
                                unsigned short* __restrict__ Wt_h1, int n2) {
    int i = blockIdx.x * blockDim.x + threadIdx.x;
    if (i < n2) {
        float2 v = *reinterpret_cast<const float2*>(&x[(size_t)i * 2]);
        xbf[i] = (unsigned)f2bf(v.x) | ((unsigned)f2bf(v.y) << 16);
        return;
    }
    int r = i - n2;
    if (r < 32768) {                 // W_in [128][256]
        int k = r >> 8, c = r & 255;
        Wt_in[(size_t)c * 128 + k] = f2bf(W_in[r]);
    } else if (r < 32768 + 65536) {  // W_hid[0] [256][256]
        r -= 32768;
        int k = r >> 8, c = r & 255;
        Wt_h0[(size_t)c * 256 + k] = f2bf(W_hid[r]);
    } else if (r < 32768 + 131072) { // W_hid[1]
        r -= 32768 + 65536;
        int k = r >> 8, c = r & 255;
        Wt_h1[(size_t)c * 256 + k] = f2bf(W_hid[65536 + r]);
    }
}

// ================ FUSED agg+GEMM layer ================
// 512 threads = 8 waves = 16 nodes (2 nodes/wave, 32 lanes/node, r6 gather structure).
// Phase 1: gather K cols/node into fp32 regs (8-deep edge unroll) [+ LN affine of prev layer].
// Phase 2: pack bf16 -> 16-row swizzled LDS A-tile (16*K*2 bytes).
// Phase 3: each wave computes 32 output cols via 16x16x32 MFMA, B-frags from L2-hot Wt.
// Epilogue: bias + leaky-relu, uint2 bf16 store, column stats via shfl + LDS + global atomics.
template<int K, int NN, bool AFF>
__launch_bounds__(512, 4)
__global__ void fused_aggemm(const unsigned* __restrict__ X, const unsigned short* __restrict__ Wt,
                             const float* __restrict__ bias,
                             const float* __restrict__ ssum, const float* __restrict__ ssq,
                             const float* __restrict__ gg, const float* __restrict__ be, float invN,
                             unsigned short* __restrict__ out,
                             const unsigned* __restrict__ row_ptr, const uint2* __restrict__ csr,
                             const float* __restrict__ dinv,
                             float* __restrict__ stat_sum, float* __restrict__ stat_sq, int N) {
    constexpr int UPL = K / 64;          // uints per lane (32 lanes/node)
    constexpr int PC  = UPL * 2;         // fp32 cols per lane
    constexpr unsigned RSU = K / 2;      // input row stride in uints

    __shared__ char atile[16 * K * 2];
    __shared__ float sL[AFF ? K : 1], tL[AFF ? K : 1];
    __shared__ float csum[NN], csq[NN];

    const int tid = threadIdx.x;

    if constexpr (AFF) {
        for (int i = tid; i < K; i += 512) {
            float mu = ssum[i] * invN;
            float var = ssq[i] * invN - mu * mu;
            float s = gg[i] * rsqrtf(var + EPS_LN);
            sL[i] = s; tL[i] = be[i] - mu * s;
        }
    }
    for (int i = tid; i < NN; i += 512) { csum[i] = 0.f; csq[i] = 0.f; }
    __syncthreads();

    // ---------- gather ----------
    const int rrow = tid >> 5;           // 0..15 (row in block tile)
    const int ll = tid & 31;
    const int node = blockIdx.x * 16 + rrow;
    const unsigned cu = (unsigned)ll * UPL;

    float acc[PC];
    #pragma unroll
    for (int j = 0; j < PC; ++j) acc[j] = 0.f;
    float wsum = 0.f;

    if (node < N) {
        float di = dinv[node];
        float w0 = di * di;
        wsum = w0;
        {
            const unsigned* xr = X + (size_t)((unsigned)node * RSU + cu);
            if constexpr (UPL == 4) {
                uint4 v = *reinterpret_cast<const uint4*>(xr);
                unsigned uu[4] = {v.x, v.y, v.z, v.w};
                #pragma unroll
                for (int q = 0; q < 4; ++q) {
                    acc[q * 2 + 0] = w0 * bf_lo(uu[q]);
                    acc[q * 2 + 1] = w0 * bf_hi(uu[q]);
                }
            } else {
                uint2 v = *reinterpret_cast<const uint2*>(xr);
                acc[0] = w0 * bf_lo(v.x); acc[1] = w0 * bf_hi(v.x);
                acc[2] = w0 * bf_lo(v.y); acc[3] = w0 * bf_hi(v.y);
            }
        }
        unsigned e0 = row_ptr[node];
        unsigned e1 = row_ptr[node + 1];
        unsigned cnt = e1 - e0;
        unsigned full = cnt & ~7u;

        for (unsigned i = 0; i < full; i += 8) {
            uint2 p[8];
            #pragma unroll
            for (int u = 0; u < 8; ++u) p[u] = csr[e0 + i + u];
            if constexpr (UPL == 4) {
                uint4 v[8];
                #pragma unroll
                for (int u = 0; u < 8; ++u)
                    v[u] = *reinterpret_cast<const uint4*>(X + (size_t)(p[u].x * RSU + cu));
                #pragma unroll
                for (int u = 0; u < 8; ++u) {
                    float f = __uint_as_float(p[u].y);
                    unsigned uu[4] = {v[u].x, v[u].y, v[u].z, v[u].w};
                    #pragma unroll
                    for (int q = 0; q < 4; ++q) {
                        acc[q * 2 + 0] += f * bf_lo(uu[q]);
                        acc[q * 2 + 1] += f * bf_hi(uu[q]);
                    }
                    wsum += f;
                }
            } else {
                uint2 v[8];
                #pragma unroll
                for (int u = 0; u < 8; ++u)
                    v[u] = *reinterpret_cast<const uint2*>(X + (size_t)(p[u].x * RSU + cu));
                #pragma unroll
                for (int u = 0; u < 8; ++u) {
                    float f = __uint_as_float(p[u].y);
                    acc[0] += f * bf_lo(v[u].x); acc[1] += f * bf_hi(v[u].x);
                    acc[2] += f * bf_lo(v[u].y); acc[3] += f * bf_hi(v[u].y);
                    wsum += f;
                }
            }
        }
        for (unsigned i = full; i < cnt; ++i) {
            uint2 p = csr[e0 + i];
            float f = __uint_as_float(p.y);
            if constexpr (UPL == 4) {
                uint4 v = *reinterpret_cast<const uint4*>(X + (size_t)(p.x * RSU + cu));
                unsigned uu[4] = {v.x, v.y, v.z, v.w};
                #pragma unroll
                for (int q = 0; q < 4; ++q) {
                    acc[q * 2 + 0] += f * bf_lo(uu[q]);
                    acc[q * 2 + 1] += f * bf_hi(uu[q]);
                }
            } else {
                uint2 v = *reinterpret_cast<const uint2*>(X + (size_t)(p.x * RSU + cu));
                acc[0] += f * bf_lo(v.x); acc[1] += f * bf_hi(v.x);
                acc[2] += f * bf_lo(v.y); acc[3] += f * bf_hi(v.y);
            }
            wsum += f;
        }

        if constexpr (AFF) {
            int col = ll * PC;
            #pragma unroll
            for (int j = 0; j < PC; ++j)
                acc[j] = sL[col + j] * acc[j] + tL[col + j] * wsum;
        }
    }

    // ---------- pack bf16 -> swizzled LDS A-tile ----------
    {
        char* myrow = atile + rrow * (K * 2);
        if constexpr (UPL == 4) {
            uint4 pk;
            pk.x = (unsigned)f2bf(acc[0]) | ((unsigned)f2bf(acc[1]) << 16);
            pk.y = (unsigned)f2bf(acc[2]) | ((unsigned)f2bf(acc[3]) << 16);
            pk.z = (unsigned)f2bf(acc[4]) | ((unsigned)f2bf(acc[5]) << 16);
            pk.w = (unsigned)f2bf(acc[6]) | ((unsigned)f2bf(acc[7]) << 16);
            int off = (ll * 16) ^ ((rrow & 7) << 4);
            *reinterpret_cast<uint4*>(myrow + off) = pk;
        } else {
            uint2 pk;
            pk.x = (unsigned)f2bf(acc[0]) | ((unsigned)f2bf(acc[1]) << 16);
            pk.y = (unsigned)f2bf(acc[2]) | ((unsigned)f2bf(acc[3]) << 16);
            int off = (ll * 8) ^ ((rrow & 7) << 4);
            *reinterpret_cast<uint2*>(myrow + off) = pk;
        }
    }
    __syncthreads();

    // ---------- MFMA: 16 rows x [32 cols per wave] ----------
    const int w = tid >> 6;              // 0..7
    const int lane = tid & 63;
    const int frow = lane & 15;
    const int kgrp = lane >> 4;
    f32x4 macc[2] = {};

    #pragma unroll
    for (int kt = 0; kt < K / 32; ++kt) {
        int aoff = frow * (K * 2) + ((kt * 64 + kgrp * 16) ^ ((frow & 7) << 4));
        bf16x8 af = *reinterpret_cast<const bf16x8*>(atile + aoff);
        #pragma unroll
        for (int n = 0; n < 2; ++n) {
            int c = w * 32 + n * 16 + frow;
            bf16x8 bfr = *reinterpret_cast<const bf16x8*>(Wt + (size_t)c * K + kt * 32 + kgrp * 8);
            macc[n] = __builtin_amdgcn_mfma_f32_16x16x32_bf16(bfr, af, macc[n], 0, 0, 0);
        }
    }

    // ---------- epilogue ----------
    const int orow = blockIdx.x * 16 + frow;
    const bool rok = orow < N;
    #pragma unroll
    for (int n = 0; n < 2; ++n) {
        const int c0 = w * 32 + n * 16 + kgrp * 4;
        float4 b4 = *reinterpret_cast<const float4*>(&bias[c0]);
        float f0 = macc[n][0] + b4.x;
        float f1 = macc[n][1] + b4.y;
        float f2 = macc[n][2] + b4.z;
        float f3 = macc[n][3] + b4.w;
        f0 = f0 > 0.f ? f0 : 0.01f * f0;
        f1 = f1 > 0.f ? f1 : 0.01f * f1;
        f2 = f2 > 0.f ? f2 : 0.01f * f2;
        f3 = f3 > 0.f ? f3 : 0.01f * f3;
        float ps[4], pq[4];
        if (rok) {
            uint2 pk;
            pk.x = (unsigned)f2bf(f0) | ((unsigned)f2bf(f1) << 16);
            pk.y = (unsigned)f2bf(f2) | ((unsigned)f2bf(f3) << 16);
            *reinterpret_cast<uint2*>(&out[(size_t)orow * NN + c0]) = pk;
            ps[0] = f0; ps[1] = f1; ps[2] = f2; ps[3] = f3;
            pq[0] = f0 * f0; pq[1] = f1 * f1; pq[2] = f2 * f2; pq[3] = f3 * f3;
        } else {
            ps[0] = ps[1] = ps[2] = ps[3] = 0.f;
            pq[0] = pq[1] = pq[2] = pq[3] = 0.f;
        }
        #pragma unroll
        for (int s = 1; s < 16; s <<= 1) {
            #pragma unroll
            for (int j = 0; j < 4; ++j) {
                ps[j] += __shfl_xor(ps[j], s);
                pq[j] += __shfl_xor(pq[j], s);
            }
        }
        if (frow == 0) {
            #pragma unroll
            for (int j = 0; j < 4; ++j) {
                atomicAdd(&csum[c0 + j], ps[j]);
                atomicAdd(&csq[c0 + j], pq[j]);
            }
        }
    }
    __syncthreads();
    for (int i = tid; i < NN; i += 512) {
        atomicAdd(&stat_sum[i], csum[i]);
        atomicAdd(&stat_sq[i], csq[i]);
    }
}

// ---------------- final aggregation (128-wide, fp32 out, lrelu + rank-1 + bias) ----------------
template<int UPL, bool AFF, bool FINAL>
__global__ void aggregate_bf(const unsigned* __restrict__ X, void* __restrict__ outp,
                             const unsigned* __restrict__ row_ptr, const uint2* __restrict__ csr,
                             const float* __restrict__ dinv,
                             const float* __restrict__ tW, const float* __restrict__ bias, int N) {
    constexpr int C = UPL * 64;
    constexpr unsigned RSU = C / 2;
    constexpr int PC = UPL * 2;

    int node = blockIdx.x * 8 + (threadIdx.x >> 5);
    if (node >= N) return;
    int ll = threadIdx.x & 31;
    unsigned cu = (unsigned)ll * UPL;

    float di = dinv[node];
    float w0 = di * di;
    float acc[PC];
    float wsum = w0;
    {
        const unsigned* xr = X + (size_t)((unsigned)node * RSU + cu);
        uint2 v = *reinterpret_cast<const uint2*>(xr);
        acc[0] = w0 * bf_lo(v.x); acc[1] = w0 * bf_hi(v.x);
        acc[2] = w0 * bf_lo(v.y); acc[3] = w0 * bf_hi(v.y);
    }
    unsigned e0 = row_ptr[node];
    unsigned e1 = row_ptr[node + 1];
    unsigned cnt = e1 - e0;
    unsigned full = cnt & ~7u;

    for (unsigned i = 0; i < full; i += 8) {
        uint2 p[8];
        #pragma unroll
        for (int u = 0; u < 8; ++u) p[u] = csr[e0 + i + u];
        uint2 v[8];
        #pragma unroll
        for (int u = 0; u < 8; ++u)
            v[u] = *reinterpret_cast<const uint2*>(X + (size_t)(p[u].x * RSU + cu));
        #pragma unroll
        for (int u = 0; u < 8; ++u) {
            float f = __uint_as_float(p[u].y);
            acc[0] += f * bf_lo(v[u].x); acc[1] += f * bf_hi(v[u].x);
            acc[2] += f * bf_lo(v[u].y); acc[3] += f * bf_hi(v[u].y);
            wsum += f;
        }
    }
    for (unsigned i = full; i < cnt; ++i) {
        uint2 p = csr[e0 + i];
        uint2 v = *reinterpret_cast<const uint2*>(X + (size_t)(p.x * RSU + cu));
        float f = __uint_as_float(p.y);
        acc[0] += f * bf_lo(v.x); acc[1] += f * bf_hi(v.x);
        acc[2] += f * bf_lo(v.y); acc[3] += f * bf_hi(v.y);
        wsum += f;
    }

    int col = ll * PC;
    float z[PC];
    #pragma unroll
    for (int j = 0; j < PC; ++j) {
        float f = acc[j];
        f = f + wsum * tW[col + j] + bias[col + j];
        f = f > 0.f ? f : 0.01f * f;
        z[j] = f;
    }
    float* of = (float*)outp;
    *reinterpret_cast<float4*>(&of[(size_t)node * C + col]) = make_float4(z[0], z[1], z[2], z[3]);
}

// ---------------- bf16 MFMA GEMM (layer 4): out[M,128] = Z[M,256] @ Wt^T ----------------
template<int K, int NN, bool EPI>
__launch_bounds__(256)
__global__ void gemm_mfma(const unsigned short* __restrict__ Z, const unsigned short* __restrict__ Wt,
                          const float* __restrict__ bias, unsigned short* __restrict__ out,
                          float* __restrict__ stat_sum, float* __restrict__ stat_sq, int M) {
    __shared__ char smem[32768];

    const int tid = threadIdx.x;
    const int lane = tid & 63;
    const int w = tid >> 6;
    const int wr = (w >> 1) * 64;
    const int wc = (w & 1) * 64;
    const int rowBase = blockIdx.x * 128;
    const int colBase = blockIdx.y * 128;
    const int frow = lane & 15;
    const int kgrp = lane >> 4;

    f32x4 acc[4][4] = {};

    for (int kt = 0; kt < K / 64; ++kt) {
        #pragma unroll
        for (int i = 0; i < 4; ++i) {
            int g = (i * 4 + w) * 64 + lane;
            int r = g >> 3;
            int bl = (g & 7) * 16;
            int bg = bl ^ ((r & 7) << 4);
            const char* src = (const char*)Z + (((size_t)(rowBase + r) * K + kt * 64) << 1) + bg;
            async16(&smem[(i * 4 + w) * 1024], src);
        }
        #pragma unroll
        for (int i = 0; i < 4; ++i) {
            int g = (i * 4 + w) * 64 + lane;
            int r = g >> 3;
            int bl = (g & 7) * 16;
            int bg = bl ^ ((r & 7) << 4);
            const char* src = (const char*)Wt + (((size_t)(colBase + r) * K + kt * 64) << 1) + bg;
            async16(&smem[16384 + (i * 4 + w) * 1024], src);
        }
        __syncthreads();
        #pragma unroll
        for (int kk = 0; kk < 2; ++kk) {
            const int kbyte = kk * 64 + kgrp * 16;
            bf16x8 af[4], bfr[4];
            #pragma unroll
            for (int m = 0; m < 4; ++m) {
                int r = wr + m * 16 + frow;
                af[m] = *reinterpret_cast<const bf16x8*>(&smem[r * 128 + (kbyte ^ ((r & 7) << 4))]);
            }
            #pragma unroll
            for (int n = 0; n < 4; ++n) {
                int c = wc + n * 16 + frow;
                bfr[n] = *reinterpret_cast<const bf16x8*>(&smem[16384 + c * 128 + (kbyte ^ ((c & 7) << 4))]);
            }
            #pragma unroll
            for (int m = 0; m < 4; ++m)
                #pragma unroll
                for (int n = 0; n < 4; ++n)
                    acc[m][n] = __builtin_amdgcn_mfma_f32_16x16x32_bf16(bfr[n], af[m], acc[m][n], 0, 0, 0);
        }
        __syncthreads();
    }

    #pragma unroll
    for (int n = 0; n < 4; ++n) {
        const int c_local = wc + n * 16 + kgrp * 4;
        const int col = colBase + c_local;
        #pragma unroll
        for (int m = 0; m < 4; ++m) {
            int row = rowBase + wr + m * 16 + frow;
            if (row < M) {
                uint2 pk;
                pk.x = (unsigned)f2bf(acc[m][n][0]) | ((unsigned)f2bf(acc[m][n][1]) << 16);
                pk.y = (unsigned)f2bf(acc[m][n][2]) | ((unsigned)f2bf(acc[m][n][3]) << 16);
                *reinterpret_cast<uint2*>(&out[(size_t)row * NN + col]) = pk;
            }
        }
    }
}

// ---------------- W_out prep: Wt = bf16(diag(s3)W), tW = t3 @ W  (s,t from L3 stats) ----------------
__global__ void prep_wout_tw(const float* __restrict__ W,
                             const float* __restrict__ ssum, const float* __restrict__ ssq,
                             const float* __restrict__ gg, const float* __restrict__ be, float invN,
                             unsigned short* __restrict__ Wt, float* __restrict__ tW) {
    if (blockIdx.x < 128) {
        int idx = blockIdx.x * 256 + threadIdx.x;   // = k*128+c
        int k = idx >> 7, c = idx & 127;
        float mu = ssum[k] * invN;
        float var = ssq[k] * invN - mu * mu;
        float s = gg[k] * rsqrtf(var + EPS_LN);
        Wt[(size_t)c * 256 + k] = f2bf(s * W[idx]);
    } else {
        int c = threadIdx.x;
        if (c < 128) {
            float acc = 0.f;
            for (int k = 0; k < 256; ++k) {
                float mu = ssum[k] * invN;
                float var = ssq[k] * invN - mu * mu;
                float s = gg[k] * rsqrtf(var + EPS_LN);
                float t = be[k] - mu * s;
                acc += t * W[k * 128 + c];
            }
            tW[c] = acc;
        }
    }
}

// ---------------- fused column stats + raw graph pool over fp32 A[N][128] ----------------
__global__ void stats_pool_kernel(const float* __restrict__ A, const int* __restrict__ batch,
                                  float* __restrict__ stat_sum, float* __restrict__ stat_sq,
                                  float* __restrict__ psums, float* __restrict__ pcnt, int N) {
    int c = threadIdx.x;  // 128
    int n0 = blockIdx.x * 256;
    if (n0 >= N) return;
    int n1 = min(n0 + 256, N);
    float cs = 0.f, cq = 0.f;
    float acc = 0.f, cacc = 0.f;
    int curg = -1;
    for (int n = n0; n < n1; ++n) {
        float v = A[(size_t)n * 128 + c];
        cs += v; cq += v * v;
        int g = batch[n];
        if (g != curg) {
            if (curg >= 0) {
                atomicAdd(&psums[curg * 128 + c], acc);
                if (c == 0) atomicAdd(&pcnt[curg], cacc);
            }
            acc = 0.f; cacc = 0.f; curg = g;
        }
        acc += v;
        cacc += 1.f;
    }
    if (curg >= 0) {
        atomicAdd(&psums[curg * 128 + c], acc);
        if (c == 0) atomicAdd(&pcnt[curg], cacc);
    }
    atomicAdd(&stat_sum[c], cs);
    atomicAdd(&stat_sq[c], cq);
}

__global__ void divide_kernel(const float* __restrict__ psums, const float* __restrict__ pcnt,
                              const float* __restrict__ ssum, const float* __restrict__ ssq,
                              const float* __restrict__ gg, const float* __restrict__ be, float invN,
                              float* __restrict__ out) {
    int i = blockIdx.x * blockDim.x + threadIdx.x;
    if (i < 64 * 128) {
        int g = i >> 7, c = i & 127;
        float mu = ssum[c] * invN;
        float var = ssq[c] * invN - mu * mu;
        float s = gg[c] * rsqrtf(var + EPS_LN);
        float t = be[c] - mu * s;
        float cnt = pcnt[g];
        out[i] = (cnt > 0.f) ? s * (psums[i] / cnt) + t : 0.f;
    }
}

// ---------------- launch ----------------
extern "C" void kernel_launch(void* const* d_in, const int* in_sizes, int n_in,
                              void* d_out, int out_size, void* d_ws, size_t ws_size,
                              hipStream_t stream) {
    const float* x      = (const float*)d_in[0];
    const float* W_in   = (const float*)d_in[1];
    const float* b_in   = (const float*)d_in[2];
    const float* g_in   = (const float*)d_in[3];
    const float* be_in  = (const float*)d_in[4];
    const float* W_hid  = (const float*)d_in[5];
    const float* b_hid  = (const float*)d_in[6];
    const float* g_hid  = (const float*)d_in[7];
    const float* be_hid = (const float*)d_in[8];
    const float* W_out  = (const float*)d_in[9];
    const float* b_out  = (const float*)d_in[10];
    const float* g_out  = (const float*)d_in[11];
    const float* be_out = (const float*)d_in[12];
    const int*   eidx   = (const int*)d_in[13];
    const int*   batch  = (const int*)d_in[14];
    float* out = (float*)d_out;

    const int N = in_sizes[14];          // 100000
    const int E = in_sizes[13] / 2;      // 3200000
    const int Npad = ((N + 127) / 128) * 128;
    const int NB = (N + 511) / 512;
    const int* e_src = eidx;
    const int* e_dst = eidx + E;

    char* ws = (char*)d_ws;
    size_t off = 0;
    auto alloc = [&](size_t bytes) -> void* {
        void* p = ws + off;
        off = (off + bytes + 255) & ~(size_t)255;
        return p;
    };
    char* B1 = (char*)alloc((size_t)Npad * 256 * 2);
    char* B2 = (char*)alloc((size_t)Npad * 256 * 2);
    unsigned* deg      = (unsigned*)alloc((size_t)N * 4);
    float*    dinv     = (float*)alloc((size_t)N * 4);
    unsigned* row_ptr  = (unsigned*)alloc((size_t)(N + 1) * 4);
    unsigned* cursor   = (unsigned*)alloc((size_t)N * 4);
    unsigned* part     = (unsigned*)alloc(256 * 4);
    uint2*    csr      = (uint2*)alloc((size_t)E * 8);
    unsigned short* Wt_in  = (unsigned short*)alloc(256 * 128 * 2);
    unsigned short* Wt_h0  = (unsigned short*)alloc(256 * 256 * 2);
    unsigned short* Wt_h1  = (unsigned short*)alloc(256 * 256 * 2);
    unsigned short* Wt_out = (unsigned short*)alloc(128 * 256 * 2);
    float*    tW       = (float*)alloc(128 * 4);
    float*    stats    = (float*)alloc(4 * 512 * 4);
    float*    psums    = (float*)alloc(64 * 128 * 4);
    float*    pcnt     = (float*)alloc(64 * 4);

    float* s1 = stats + 0 * 512, *q1 = s1 + 256;
    float* s2 = stats + 1 * 512, *q2 = s2 + 256;
    float* s3 = stats + 2 * 512, *q3 = s3 + 256;
    float* s4 = stats + 3 * 512, *q4 = s4 + 256;

    const float invN = 1.0f / (float)N;

    hipMemsetAsync(deg, 0, (size_t)N * 4, stream);
    hipMemsetAsync(stats, 0, ((char*)pcnt + 64 * 4) - (char*)stats, stream);

    int egrid = (E + 255) / 256;
    count_deg_kernel<<<egrid, 256, 0, stream>>>(e_dst, E, deg);
    block_sums_kernel<<<NB, 256, 0, stream>>>(deg, part, N);
    scan_part_kernel<<<1, 256, 0, stream>>>(part, row_ptr, NB, N);
    scan_blocks_kernel<<<NB, 256, 0, stream>>>(deg, part, row_ptr, cursor, dinv, N);
    fill_csr_kernel<<<egrid, 256, 0, stream>>>(e_src, e_dst, dinv, E, cursor, csr);

    {
        int total = N * 64 + 32768 + 65536 + 65536;
        prep_all_kernel<<<(total + 255) / 256, 256, 0, stream>>>(
            x, (unsigned*)B2, W_in, Wt_in, W_hid, Wt_h0, Wt_h1, N * 64);
    }

    const int fusedGrid = (N + 15) / 16;

    // Layer 1: fused agg(x,128) + GEMM(128->256) + stats1
    fused_aggemm<128, 256, false><<<fusedGrid, 512, 0, stream>>>(
        (const unsigned*)B2, Wt_in, b_in, nullptr, nullptr, nullptr, nullptr, invN,
        (unsigned short*)B1, row_ptr, csr, dinv, s1, q1, N);

    // Layer 2: fused agg(aff1(h1),256) + GEMM + stats2
    fused_aggemm<256, 256, true><<<fusedGrid, 512, 0, stream>>>(
        (const unsigned*)B1, Wt_h0, b_hid, s1, q1, g_in, be_in, invN,
        (unsigned short*)B2, row_ptr, csr, dinv, s2, q2, N);

    // Layer 3
    fused_aggemm<256, 256, true><<<fusedGrid, 512, 0, stream>>>(
        (const unsigned*)B2, Wt_h1, b_hid + 256, s2, q2, g_hid, be_hid, invN,
        (unsigned short*)B1, row_ptr, csr, dinv, s3, q3, N);

    // Layer 4: fold LN3 affine into W_out; GEMM(256->128); final aggregate
    prep_wout_tw<<<129, 256, 0, stream>>>(W_out, s3, q3, g_hid + 256, be_hid + 256, invN, Wt_out, tW);
    gemm_mfma<256, 128, false><<<dim3(Npad / 128, 1), 256, 0, stream>>>(
        (const unsigned short*)B1, Wt_out, nullptr, (unsigned short*)B2, nullptr, nullptr, N);
    aggregate_bf<2, false, true><<<(N + 7) / 8, 256, 0, stream>>>(
        (const unsigned*)B2, B1, row_ptr, csr, dinv, tW, b_out, N);

    stats_pool_kernel<<<(N + 255) / 256, 128, 0, stream>>>(
        (const float*)B1, batch, s4, q4, psums, pcnt, N);
    divide_kernel<<<(64 * 128 + 255) / 256, 256, 0, stream>>>(
        psums, pcnt, s4, q4, g_out, be_out, invN, out);
}

// Round 8
// 1153.412 us; speedup vs baseline: 1.2713x; 1.2713x over previous
//
#include <hip/hip_runtime.h>
#include <stdint.h>

#define EPS_LN 1e-5f

typedef short bf16x8 __attribute__((ext_vector_type(8)));
typedef float f32x4  __attribute__((ext_vector_type(4)));

__device__ __forceinline__ unsigned short f2bf(float f) {
    unsigned u = __float_as_uint(f);
    unsigned r = (u + 0x7fffu + ((u >> 16) & 1u)) >> 16;
    return (unsigned short)r;
}
__device__ __forceinline__ float bf_lo(unsigned u) { return __uint_as_float(u << 16); }
__device__ __forceinline__ float bf_hi(unsigned u) { return __uint_as_float(u & 0xffff0000u); }

__device__ __forceinline__ void async16(void* lds, const void* g) {
    __builtin_amdgcn_global_load_lds(
        (const __attribute__((address_space(1))) unsigned int*)g,
        (__attribute__((address_space(3))) unsigned int*)lds, 16, 0, 0);
}

// ---------------- fused setup: degree histogram (+rank) | x->bf16 | weight transposes ----------------
__global__ void setup_kernel(const int* __restrict__ dst, int E,
                             unsigned* __restrict__ deg, unsigned* __restrict__ rank,
                             const float* __restrict__ x, unsigned* __restrict__ xbf, int n2,
                             const float* __restrict__ W_in, unsigned short* __restrict__ Wt_in,
                             const float* __restrict__ W_hid, unsigned short* __restrict__ Wt_h0,
                             unsigned short* __restrict__ Wt_h1) {
    int i = blockIdx.x * blockDim.x + threadIdx.x;
    if (i < E) {
        rank[i] = atomicAdd(&deg[dst[i]], 1u);
        return;
    }
    int j = i - E;
    if (j < n2) {
        float2 v = *reinterpret_cast<const float2*>(&x[(size_t)j * 2]);
        xbf[j] = (unsigned)f2bf(v.x) | ((unsigned)f2bf(v.y) << 16);
        return;
    }
    int r = j - n2;
    if (r < 32768) {                 // W_in [128][256]
        int k = r >> 8, c = r & 255;
        Wt_in[(size_t)c * 128 + k] = f2bf(W_in[r]);
    } else if (r < 32768 + 65536) {  // W_hid[0] [256][256]
        r -= 32768;
        int k = r >> 8, c = r & 255;
        Wt_h0[(size_t)c * 256 + k] = f2bf(W_hid[r]);
    } else if (r < 32768 + 131072) { // W_hid[1]
        r -= 32768 + 65536;
        int k = r >> 8, c = r & 255;
        Wt_h1[(size_t)c * 256 + k] = f2bf(W_hid[65536 + r]);
    }
}

// ---------------- scan chain ----------------
__global__ void block_sums_kernel(const unsigned* __restrict__ deg, unsigned* __restrict__ part, int N) {
    __shared__ unsigned s[256];
    int t = threadIdx.x;
    int i0 = blockIdx.x * 512 + t * 2;
    unsigned a = (i0 < N) ? deg[i0] : 0u;
    unsigned b = (i0 + 1 < N) ? deg[i0 + 1] : 0u;
    s[t] = a + b;
    __syncthreads();
    for (int off = 128; off > 0; off >>= 1) {
        if (t < off) s[t] += s[t + off];
        __syncthreads();
    }
    if (t == 0) part[blockIdx.x] = s[0];
}

__global__ void scan_part_kernel(unsigned* __restrict__ part, unsigned* __restrict__ row_ptr,
                                 int NB, int N) {
    __shared__ unsigned s[256];
    int t = threadIdx.x;
    unsigned v = (t < NB) ? part[t] : 0u;
    s[t] = v;
    __syncthreads();
    for (int off = 1; off < 256; off <<= 1) {
        unsigned u = (t >= off) ? s[t - off] : 0u;
        __syncthreads();
        s[t] += u;
        __syncthreads();
    }
    if (t < NB) part[t] = s[t] - v;
    if (t == 255) row_ptr[N] = s[255];
}

// local scan + row_ptr + dinv (no cursor needed with rank trick)
__global__ void scan_blocks_kernel(const unsigned* __restrict__ deg, const unsigned* __restrict__ part,
                                   unsigned* __restrict__ row_ptr, float* __restrict__ dinv, int N) {
    __shared__ unsigned s[256];
    int t = threadIdx.x;
    int i0 = blockIdx.x * 512 + t * 2;
    unsigned a = (i0 < N) ? deg[i0] : 0u;
    unsigned b = (i0 + 1 < N) ? deg[i0 + 1] : 0u;
    unsigned pair = a + b;
    s[t] = pair;
    __syncthreads();
    for (int off = 1; off < 256; off <<= 1) {
        unsigned u = (t >= off) ? s[t - off] : 0u;
        __syncthreads();
        s[t] += u;
        __syncthreads();
    }
    unsigned excl = s[t] - pair + part[blockIdx.x];
    if (i0 < N) {
        row_ptr[i0] = excl;
        dinv[i0] = rsqrtf((float)(a + 1u));
    }
    if (i0 + 1 < N) {
        row_ptr[i0 + 1] = excl + a;
        dinv[i0 + 1] = rsqrtf((float)(b + 1u));
    }
}

// fill CSR: 4-byte entries (quant15(dinv[src]) << 17) | src ; pos via row_ptr + rank (no atomics)
__global__ void fill_csr_kernel(const int* __restrict__ src, const int* __restrict__ dst,
                                const unsigned* __restrict__ rank, const unsigned* __restrict__ row_ptr,
                                const float* __restrict__ dinv, int E, unsigned* __restrict__ csr) {
    int e = blockIdx.x * blockDim.x + threadIdx.x;
    if (e < E) {
        int d = dst[e];
        int s = src[e];
        unsigned pos = row_ptr[d] + rank[e];
        unsigned wq = __float2uint_rn(dinv[s] * 32767.f);
        csr[pos] = (wq << 17) | (unsigned)s;
    }
}

// ---------------- aggregation: 2 nodes per wave, 32 lanes/node, 8-deep edge unroll ----------------
// UPL = uints per lane (4 -> 256 cols, 2 -> 128 cols). 8 nodes per 256-thread block.
// AFF: LN affine of previous layer computed from stats on the fly (LDS-staged s,t); bf16 out.
// FINAL: bf16 out = lrelu(sum + wsum*tW + bias).
template<int UPL, bool AFF, bool FINAL>
__global__ void aggregate_bf(const unsigned* __restrict__ X, unsigned* __restrict__ outp,
                             const unsigned* __restrict__ row_ptr, const unsigned* __restrict__ csr,
                             const float* __restrict__ dinv,
                             const float* __restrict__ ssum, const float* __restrict__ ssq,
                             const float* __restrict__ gg, const float* __restrict__ be, float invN,
                             const float* __restrict__ tW, const float* __restrict__ bias, int N) {
    constexpr int C = UPL * 64;          // columns (bf16)
    constexpr unsigned RSU = C / 2;      // row stride in uints
    constexpr int PC = UPL * 2;          // cols per lane

    __shared__ float sL[AFF ? C : 1], tL[AFF ? C : 1];
    if constexpr (AFF) {
        for (int i = threadIdx.x; i < C; i += 256) {
            float mu = ssum[i] * invN;
            float var = ssq[i] * invN - mu * mu;
            float s = gg[i] * rsqrtf(var + EPS_LN);
            sL[i] = s;
            tL[i] = be[i] - mu * s;
        }
        __syncthreads();
    }

    int node = blockIdx.x * 8 + (threadIdx.x >> 5);
    if (node >= N) return;
    int ll = threadIdx.x & 31;
    unsigned cu = (unsigned)ll * UPL;

    float di = dinv[node];
    float dscale = di * (1.f / 32767.f);
    float w0 = di * di;
    float acc[PC];
    float wsum = w0;
    {
        const unsigned* xr = X + (size_t)((unsigned)node * RSU + cu);
        if constexpr (UPL == 4) {
            uint4 v = *reinterpret_cast<const uint4*>(xr);
            unsigned uu[4] = {v.x, v.y, v.z, v.w};
            #pragma unroll
            for (int q = 0; q < 4; ++q) {
                acc[q * 2 + 0] = w0 * bf_lo(uu[q]);
                acc[q * 2 + 1] = w0 * bf_hi(uu[q]);
            }
        } else {
            uint2 v = *reinterpret_cast<const uint2*>(xr);
            acc[0] = w0 * bf_lo(v.x); acc[1] = w0 * bf_hi(v.x);
            acc[2] = w0 * bf_lo(v.y); acc[3] = w0 * bf_hi(v.y);
        }
    }
    unsigned e0 = row_ptr[node];
    unsigned e1 = row_ptr[node + 1];
    unsigned cnt = e1 - e0;
    unsigned full = cnt & ~7u;

    for (unsigned i = 0; i < full; i += 8) {
        unsigned p[8];
        #pragma unroll
        for (int u = 0; u < 8; ++u) p[u] = csr[e0 + i + u];
        if constexpr (UPL == 4) {
            uint4 v[8];
            #pragma unroll
            for (int u = 0; u < 8; ++u)
                v[u] = *reinterpret_cast<const uint4*>(X + (size_t)((p[u] & 0x1FFFFu) * RSU + cu));
            #pragma unroll
            for (int u = 0; u < 8; ++u) {
                float f = (float)(p[u] >> 17) * dscale;
                unsigned uu[4] = {v[u].x, v[u].y, v[u].z, v[u].w};
                #pragma unroll
                for (int q = 0; q < 4; ++q) {
                    acc[q * 2 + 0] += f * bf_lo(uu[q]);
                    acc[q * 2 + 1] += f * bf_hi(uu[q]);
                }
                wsum += f;
            }
        } else {
            uint2 v[8];
            #pragma unroll
            for (int u = 0; u < 8; ++u)
                v[u] = *reinterpret_cast<const uint2*>(X + (size_t)((p[u] & 0x1FFFFu) * RSU + cu));
            #pragma unroll
            for (int u = 0; u < 8; ++u) {
                float f = (float)(p[u] >> 17) * dscale;
                acc[0] += f * bf_lo(v[u].x); acc[1] += f * bf_hi(v[u].x);
                acc[2] += f * bf_lo(v[u].y); acc[3] += f * bf_hi(v[u].y);
                wsum += f;
            }
        }
    }
    for (unsigned i = full; i < cnt; ++i) {
        unsigned p = csr[e0 + i];
        float f = (float)(p >> 17) * dscale;
        if constexpr (UPL == 4) {
            uint4 v = *reinterpret_cast<const uint4*>(X + (size_t)((p & 0x1FFFFu) * RSU + cu));
            unsigned uu[4] = {v.x, v.y, v.z, v.w};
            #pragma unroll
            for (int q = 0; q < 4; ++q) {
                acc[q * 2 + 0] += f * bf_lo(uu[q]);
                acc[q * 2 + 1] += f * bf_hi(uu[q]);
            }
        } else {
            uint2 v = *reinterpret_cast<const uint2*>(X + (size_t)((p & 0x1FFFFu) * RSU + cu));
            acc[0] += f * bf_lo(v.x); acc[1] += f * bf_hi(v.x);
            acc[2] += f * bf_lo(v.y); acc[3] += f * bf_hi(v.y);
        }
        wsum += f;
    }

    int col = ll * PC;
    float z[PC];
    #pragma unroll
    for (int j = 0; j < PC; ++j) {
        float f = acc[j];
        if constexpr (AFF) f = sL[col + j] * f + tL[col + j] * wsum;
        if constexpr (FINAL) {
            f = f + wsum * tW[col + j] + bias[col + j];
            f = f > 0.f ? f : 0.01f * f;
        }
        z[j] = f;
    }
    if constexpr (UPL == 4) {
        uint4 pk;
        pk.x = (unsigned)f2bf(z[0]) | ((unsigned)f2bf(z[1]) << 16);
        pk.y = (unsigned)f2bf(z[2]) | ((unsigned)f2bf(z[3]) << 16);
        pk.z = (unsigned)f2bf(z[4]) | ((unsigned)f2bf(z[5]) << 16);
        pk.w = (unsigned)f2bf(z[6]) | ((unsigned)f2bf(z[7]) << 16);
        *reinterpret_cast<uint4*>(&outp[(size_t)((unsigned)node * RSU + cu)]) = pk;
    } else {
        uint2 pk;
        pk.x = (unsigned)f2bf(z[0]) | ((unsigned)f2bf(z[1]) << 16);
        pk.y = (unsigned)f2bf(z[2]) | ((unsigned)f2bf(z[3]) << 16);
        *reinterpret_cast<uint2*>(&outp[(size_t)((unsigned)node * RSU + cu)]) = pk;
    }
}

// ---------------- bf16 MFMA GEMM: out[M,NN] = Z[M,K] @ Wt^T  (Wt is [NN][K]) ----------------
// Swapped operands: lane's 4 acc regs = 4 consecutive output columns.
template<int K, int NN, bool EPI>
__launch_bounds__(256)
__global__ void gemm_mfma(const unsigned short* __restrict__ Z, const unsigned short* __restrict__ Wt,
                          const float* __restrict__ bias, unsigned short* __restrict__ out,
                          float* __restrict__ stat_sum, float* __restrict__ stat_sq, int M) {
    __shared__ char smem[32768];
    __shared__ float csum[128], csq[128];

    const int tid = threadIdx.x;
    const int lane = tid & 63;
    const int w = tid >> 6;
    const int wr = (w >> 1) * 64;
    const int wc = (w & 1) * 64;
    const int rowBase = blockIdx.x * 128;
    const int colBase = blockIdx.y * 128;
    const int frow = lane & 15;
    const int kgrp = lane >> 4;

    f32x4 acc[4][4] = {};

    for (int kt = 0; kt < K / 64; ++kt) {
        #pragma unroll
        for (int i = 0; i < 4; ++i) {
            int g = (i * 4 + w) * 64 + lane;
            int r = g >> 3;
            int bl = (g & 7) * 16;
            int bg = bl ^ ((r & 7) << 4);
            const char* src = (const char*)Z + (((size_t)(rowBase + r) * K + kt * 64) << 1) + bg;
            async16(&smem[(i * 4 + w) * 1024], src);
        }
        #pragma unroll
        for (int i = 0; i < 4; ++i) {
            int g = (i * 4 + w) * 64 + lane;
            int r = g >> 3;
            int bl = (g & 7) * 16;
            int bg = bl ^ ((r & 7) << 4);
            const char* src = (const char*)Wt + (((size_t)(colBase + r) * K + kt * 64) << 1) + bg;
            async16(&smem[16384 + (i * 4 + w) * 1024], src);
        }
        __syncthreads();
        #pragma unroll
        for (int kk = 0; kk < 2; ++kk) {
            const int kbyte = kk * 64 + kgrp * 16;
            bf16x8 af[4], bfr[4];
            #pragma unroll
            for (int m = 0; m < 4; ++m) {
                int r = wr + m * 16 + frow;
                af[m] = *reinterpret_cast<const bf16x8*>(&smem[r * 128 + (kbyte ^ ((r & 7) << 4))]);
            }
            #pragma unroll
            for (int n = 0; n < 4; ++n) {
                int c = wc + n * 16 + frow;
                bfr[n] = *reinterpret_cast<const bf16x8*>(&smem[16384 + c * 128 + (kbyte ^ ((c & 7) << 4))]);
            }
            #pragma unroll
            for (int m = 0; m < 4; ++m)
                #pragma unroll
                for (int n = 0; n < 4; ++n)
                    acc[m][n] = __builtin_amdgcn_mfma_f32_16x16x32_bf16(bfr[n], af[m], acc[m][n], 0, 0, 0);
        }
        __syncthreads();
    }

    if constexpr (EPI) {
        if (tid < 128) { csum[tid] = 0.f; csq[tid] = 0.f; }
        __syncthreads();
    }

    #pragma unroll
    for (int n = 0; n < 4; ++n) {
        const int c_local = wc + n * 16 + kgrp * 4;
        const int col = colBase + c_local;
        float4 b4 = make_float4(0.f, 0.f, 0.f, 0.f);
        if constexpr (EPI) b4 = *reinterpret_cast<const float4*>(&bias[col]);
        float ps[4] = {0.f, 0.f, 0.f, 0.f}, pq[4] = {0.f, 0.f, 0.f, 0.f};
        #pragma unroll
        for (int m = 0; m < 4; ++m) {
            int row = rowBase + wr + m * 16 + frow;
            if (row < M) {
                float f0 = acc[m][n][0] + b4.x;
                float f1 = acc[m][n][1] + b4.y;
                float f2 = acc[m][n][2] + b4.z;
                float f3 = acc[m][n][3] + b4.w;
                if constexpr (EPI) {
                    f0 = f0 > 0.f ? f0 : 0.01f * f0;
                    f1 = f1 > 0.f ? f1 : 0.01f * f1;
                    f2 = f2 > 0.f ? f2 : 0.01f * f2;
                    f3 = f3 > 0.f ? f3 : 0.01f * f3;
                }
                uint2 pk;
                pk.x = (unsigned)f2bf(f0) | ((unsigned)f2bf(f1) << 16);
                pk.y = (unsigned)f2bf(f2) | ((unsigned)f2bf(f3) << 16);
                *reinterpret_cast<uint2*>(&out[(size_t)row * NN + col]) = pk;
                if constexpr (EPI) {
                    ps[0] += f0; ps[1] += f1; ps[2] += f2; ps[3] += f3;
                    pq[0] += f0 * f0; pq[1] += f1 * f1; pq[2] += f2 * f2; pq[3] += f3 * f3;
                }
            }
        }
        if constexpr (EPI) {
            #pragma unroll
            for (int s = 1; s < 16; s <<= 1) {
                #pragma unroll
                for (int j = 0; j < 4; ++j) {
                    ps[j] += __shfl_xor(ps[j], s);
                    pq[j] += __shfl_xor(pq[j], s);
                }
            }
            if (frow == 0) {
                #pragma unroll
                for (int j = 0; j < 4; ++j) {
                    atomicAdd(&csum[c_local + j], ps[j]);
                    atomicAdd(&csq[c_local + j], pq[j]);
                }
            }
        }
    }
    if constexpr (EPI) {
        __syncthreads();
        if (tid < 128) {
            atomicAdd(&stat_sum[colBase + tid], csum[tid]);
            atomicAdd(&stat_sq[colBase + tid], csq[tid]);
        }
    }
}

// ---------------- W_out prep: Wt = bf16(diag(s3)W), tW = t3 @ W  (s,t from L3 stats) ----------------
__global__ void prep_wout_tw(const float* __restrict__ W,
                             const float* __restrict__ ssum, const float* __restrict__ ssq,
                             const float* __restrict__ gg, const float* __restrict__ be, float invN,
                             unsigned short* __restrict__ Wt, float* __restrict__ tW) {
    if (blockIdx.x < 128) {
        int idx = blockIdx.x * 256 + threadIdx.x;   // = k*128+c
        int k = idx >> 7, c = idx & 127;
        float mu = ssum[k] * invN;
        float var = ssq[k] * invN - mu * mu;
        float s = gg[k] * rsqrtf(var + EPS_LN);
        Wt[(size_t)c * 256 + k] = f2bf(s * W[idx]);
    } else {
        int c = threadIdx.x;
        if (c < 128) {
            float acc = 0.f;
            for (int k = 0; k < 256; ++k) {
                float mu = ssum[k] * invN;
                float var = ssq[k] * invN - mu * mu;
                float s = gg[k] * rsqrtf(var + EPS_LN);
                float t = be[k] - mu * s;
                acc += t * W[k * 128 + c];
            }
            tW[c] = acc;
        }
    }
}

// ---------------- fused column stats + raw graph pool over bf16 A[N][128] ----------------
__global__ void stats_pool_kernel(const unsigned short* __restrict__ A, const int* __restrict__ batch,
                                  float* __restrict__ stat_sum, float* __restrict__ stat_sq,
                                  float* __restrict__ psums, float* __restrict__ pcnt, int N) {
    int c = threadIdx.x;  // 128
    int n0 = blockIdx.x * 256;
    if (n0 >= N) return;
    int n1 = min(n0 + 256, N);
    float cs = 0.f, cq = 0.f;
    float acc = 0.f, cacc = 0.f;
    int curg = -1;
    for (int n = n0; n < n1; ++n) {
        float v = __uint_as_float((unsigned)A[(size_t)n * 128 + c] << 16);
        cs += v; cq += v * v;
        int g = batch[n];
        if (g != curg) {
            if (curg >= 0) {
                atomicAdd(&psums[curg * 128 + c], acc);
                if (c == 0) atomicAdd(&pcnt[curg], cacc);
            }
            acc = 0.f; cacc = 0.f; curg = g;
        }
        acc += v;
        cacc += 1.f;
    }
    if (curg >= 0) {
        atomicAdd(&psums[curg * 128 + c], acc);
        if (c == 0) atomicAdd(&pcnt[curg], cacc);
    }
    atomicAdd(&stat_sum[c], cs);
    atomicAdd(&stat_sq[c], cq);
}

__global__ void divide_kernel(const float* __restrict__ psums, const float* __restrict__ pcnt,
                              const float* __restrict__ ssum, const float* __restrict__ ssq,
                              const float* __restrict__ gg, const float* __restrict__ be, float invN,
                              float* __restrict__ out) {
    int i = blockIdx.x * blockDim.x + threadIdx.x;
    if (i < 64 * 128) {
        int g = i >> 7, c = i & 127;
        float mu = ssum[c] * invN;
        float var = ssq[c] * invN - mu * mu;
        float s = gg[c] * rsqrtf(var + EPS_LN);
        float t = be[c] - mu * s;
        float cnt = pcnt[g];
        out[i] = (cnt > 0.f) ? s * (psums[i] / cnt) + t : 0.f;
    }
}

// ---------------- launch ----------------
extern "C" void kernel_launch(void* const* d_in, const int* in_sizes, int n_in,
                              void* d_out, int out_size, void* d_ws, size_t ws_size,
                              hipStream_t stream) {
    const float* x      = (const float*)d_in[0];
    const float* W_in   = (const float*)d_in[1];
    const float* b_in   = (const float*)d_in[2];
    const float* g_in   = (const float*)d_in[3];
    const float* be_in  = (const float*)d_in[4];
    const float* W_hid  = (const float*)d_in[5];
    const float* b_hid  = (const float*)d_in[6];
    const float* g_hid  = (const float*)d_in[7];
    const float* be_hid = (const float*)d_in[8];
    const float* W_out  = (const float*)d_in[9];
    const float* b_out  = (const float*)d_in[10];
    const float* g_out  = (const float*)d_in[11];
    const float* be_out = (const float*)d_in[12];
    const int*   eidx   = (const int*)d_in[13];
    const int*   batch  = (const int*)d_in[14];
    float* out = (float*)d_out;

    const int N = in_sizes[14];          // 100000
    const int E = in_sizes[13] / 2;      // 3200000
    const int Npad = ((N + 127) / 128) * 128;
    const int NB = (N + 511) / 512;
    const int* e_src = eidx;
    const int* e_dst = eidx + E;

    char* ws = (char*)d_ws;
    size_t off = 0;
    auto alloc = [&](size_t bytes) -> void* {
        void* p = ws + off;
        off = (off + bytes + 255) & ~(size_t)255;
        return p;
    };
    char* B1 = (char*)alloc((size_t)Npad * 256 * 2);
    char* B2 = (char*)alloc((size_t)Npad * 256 * 2);
    unsigned* deg      = (unsigned*)alloc((size_t)N * 4);
    float*    dinv     = (float*)alloc((size_t)N * 4);
    unsigned* row_ptr  = (unsigned*)alloc((size_t)(N + 1) * 4);
    unsigned* rank     = (unsigned*)alloc((size_t)E * 4);
    unsigned* part     = (unsigned*)alloc(256 * 4);
    unsigned* csr      = (unsigned*)alloc((size_t)E * 4);
    unsigned short* Wt_in  = (unsigned short*)alloc(256 * 128 * 2);
    unsigned short* Wt_h0  = (unsigned short*)alloc(256 * 256 * 2);
    unsigned short* Wt_h1  = (unsigned short*)alloc(256 * 256 * 2);
    unsigned short* Wt_out = (unsigned short*)alloc(128 * 256 * 2);
    float*    tW       = (float*)alloc(128 * 4);
    float*    stats    = (float*)alloc(4 * 512 * 4);
    float*    psums    = (float*)alloc(64 * 128 * 4);
    float*    pcnt     = (float*)alloc(64 * 4);

    float* s1 = stats + 0 * 512, *q1 = s1 + 256;
    float* s2 = stats + 1 * 512, *q2 = s2 + 256;
    float* s3 = stats + 2 * 512, *q3 = s3 + 256;
    float* s4 = stats + 3 * 512, *q4 = s4 + 256;

    const float invN = 1.0f / (float)N;

    hipMemsetAsync(deg, 0, (size_t)N * 4, stream);
    hipMemsetAsync(stats, 0, ((char*)pcnt + 64 * 4) - (char*)stats, stream);

    // fused setup: degree+rank | x->bf16 | weight transposes
    {
        int total = E + N * 64 + 32768 + 65536 + 65536;
        setup_kernel<<<(total + 255) / 256, 256, 0, stream>>>(
            e_dst, E, deg, rank, x, (unsigned*)B2, N * 64, W_in, Wt_in, W_hid, Wt_h0, Wt_h1);
    }
    block_sums_kernel<<<NB, 256, 0, stream>>>(deg, part, N);
    scan_part_kernel<<<1, 256, 0, stream>>>(part, row_ptr, NB, N);
    scan_blocks_kernel<<<NB, 256, 0, stream>>>(deg, part, row_ptr, dinv, N);
    fill_csr_kernel<<<(E + 255) / 256, 256, 0, stream>>>(e_src, e_dst, rank, row_ptr, dinv, E, csr);

    const int aggGrid = (N + 7) / 8;
    dim3 gg256(Npad / 128, 2);

    // Layer 1: agg(x,128) -> GEMM(128->256)+stats1
    aggregate_bf<2, false, false><<<aggGrid, 256, 0, stream>>>(
        (const unsigned*)B2, (unsigned*)B1, row_ptr, csr, dinv,
        nullptr, nullptr, nullptr, nullptr, invN, nullptr, nullptr, N);
    gemm_mfma<128, 256, true><<<gg256, 256, 0, stream>>>(
        (const unsigned short*)B1, Wt_in, b_in, (unsigned short*)B2, s1, q1, N);

    // Layer 2: agg(aff1(h1),256) -> GEMM+stats2
    aggregate_bf<4, true, false><<<aggGrid, 256, 0, stream>>>(
        (const unsigned*)B2, (unsigned*)B1, row_ptr, csr, dinv,
        s1, q1, g_in, be_in, invN, nullptr, nullptr, N);
    gemm_mfma<256, 256, true><<<gg256, 256, 0, stream>>>(
        (const unsigned short*)B1, Wt_h0, b_hid, (unsigned short*)B2, s2, q2, N);

    // Layer 3
    aggregate_bf<4, true, false><<<aggGrid, 256, 0, stream>>>(
        (const unsigned*)B2, (unsigned*)B1, row_ptr, csr, dinv,
        s2, q2, g_hid, be_hid, invN, nullptr, nullptr, N);
    gemm_mfma<256, 256, true><<<gg256, 256, 0, stream>>>(
        (const unsigned short*)B1, Wt_h1, b_hid + 256, (unsigned short*)B2, s3, q3, N);

    // Layer 4: fold LN3 affine into W_out; GEMM(256->128); final aggregate (bf16 out)
    prep_wout_tw<<<129, 256, 0, stream>>>(W_out, s3, q3, g_hid + 256, be_hid + 256, invN, Wt_out, tW);
    gemm_mfma<256, 128, false><<<dim3(Npad / 128, 1), 256, 0, stream>>>(
        (const unsigned short*)B2, Wt_out, nullptr, (unsigned short*)B1, nullptr, nullptr, N);
    aggregate_bf<2, false, true><<<aggGrid, 256, 0, stream>>>(
        (const unsigned*)B1, (unsigned*)B2, row_ptr, csr, dinv,
        nullptr, nullptr, nullptr, nullptr, invN, tW, b_out, N);

    stats_pool_kernel<<<(N + 255) / 256, 128, 0, stream>>>(
        (const unsigned short*)B2, batch, s4, q4, psums, pcnt, N);
    divide_kernel<<<(64 * 128 + 255) / 256, 256, 0, stream>>>(
        psums, pcnt, s4, q4, g_out, be_out, invN, out);
}